// Round 1
// 359.826 us; speedup vs baseline: 1.0158x; 1.0158x over previous
//
#include <hip/hip_runtime.h>

// VectorQuantizer on MI355X (gfx950), v2.
// 512-thr blocks, M=256 rows (4 (b,h) lines), K=1024 codes in 32 dbuf tiles
// of 32 codes staged via global_load_lds from a PRE-SWIZZLED bf16 codebook,
// counted vmcnt(2) pipeline (never drained in-loop). Loss computed from the
// GEMM argmin value + fp32 row norms (x read exactly once). Phase 2 writes
// out via float4 gather -> XOR-swizzled LDS transpose -> dwordx4 stores.

#define DIN 256

typedef __attribute__((ext_vector_type(8))) short short8;
typedef __attribute__((ext_vector_type(4))) float float4v;
typedef __attribute__((ext_vector_type(4))) unsigned short ushort4v;

static __device__ __forceinline__ unsigned short f2bf(float f) {
  unsigned int u = __float_as_uint(f);
  unsigned int r = (u + 0x7fffu + ((u >> 16) & 1u)) >> 16;  // RNE
  return (unsigned short)r;
}

// codebook fp32 -> bf16 PRE-SWIZZLED 32-code tiles: a linear global_load_lds
// DMA of a tile lands exactly in the XOR-swizzled layout the B-fragment
// ds_read_b128s expect (slot = chunk ^ (row&7)). Also per-code ||e||^2.
__global__ void vq_prep(const float* __restrict__ e,
                        unsigned short* __restrict__ e_pre,
                        float* __restrict__ norms) {
  int wave = threadIdx.x >> 6, lane = threadIdx.x & 63;
  int k = blockIdx.x * 4 + wave;
  const float4v* src = (const float4v*)(e + k * DIN);
  float4v v = src[lane];
  float ss = v[0]*v[0] + v[1]*v[1] + v[2]*v[2] + v[3]*v[3];
  ushort4v pk;
  pk[0] = f2bf(v[0]); pk[1] = f2bf(v[1]); pk[2] = f2bf(v[2]); pk[3] = f2bf(v[3]);
  int t = k >> 5, kL = k & 31;
  int cc = lane >> 1, half = lane & 1;       // 16B chunk, 8B half
  int s = cc ^ (kL & 7);
  *(ushort4v*)(e_pre + t * 8192 + kL * 256 + s * 8 + half * 4) = pk;
  #pragma unroll
  for (int m = 1; m < 64; m <<= 1) ss += __shfl_xor(ss, m, 64);
  if (lane == 0) norms[k] = ss;
}

#define BARRIER_RAW() do { asm volatile("" ::: "memory"); \
  __builtin_amdgcn_s_barrier(); asm volatile("" ::: "memory"); } while (0)

__global__ void __launch_bounds__(512, 4)
vq_main(const float* __restrict__ xin, const float* __restrict__ e_fp,
        const unsigned short* __restrict__ e_pre,
        const float* __restrict__ norms,
        float* __restrict__ out, float* __restrict__ loss_acc) {
  // LDS: [0,16K) es buf0 | [16K,32K) es buf1   (xs prologue / qs phase2 alias [0,32K))
  //      [32K,36K) norms | [36K,38K) xn_part[64][8] | [38K..) fi[256], xna[256], prt[8]
  __shared__ char smem[41024];
  unsigned short* xs = (unsigned short*)smem;
  float* qs  = (float*)smem;
  float* nrm = (float*)(smem + 32768);
  float* xnp = (float*)(smem + 36864);
  int*   fi  = (int*)(smem + 38912);
  float* xna = (float*)(smem + 39936);
  float* prt = (float*)(smem + 40960);

  const int tid  = threadIdx.x;
  const int wave = tid >> 6, lane = tid & 63;
  const int m16  = lane & 15, quad = lane >> 4;
  const int line0 = blockIdx.x * 4;          // 4 (b,h) lines per block

  nrm[tid] = norms[tid];
  nrm[tid + 512] = norms[tid + 512];

  // ---- prologue: stage 4 lines, A-fragments -> registers, fp32 row norms ----
  short8 areg[16];
  const int wL  = wave >> 1;                 // line this wave's rows live in
  const int w32 = (wave & 1) * 32;           // w-offset within that line
  {
    const int w  = tid & 63;
    const int cg = wave;                     // chunk group 0..7
    for (int L = 0; L < 4; ++L) {
      int line = line0 + L;
      const float* xl = xin + (line >> 6) * 1048576 + (line & 63) * 64;
      __syncthreads();                       // xs / xnp free for reuse
      float ss = 0.0f;
      #pragma unroll
      for (int q8 = 0; q8 < 4; ++q8) {
        int cc = cg * 4 + q8;
        short8 pk;
        #pragma unroll
        for (int ii = 0; ii < 8; ++ii) {
          float xv = xl[(cc * 8 + ii) * 4096 + w];
          ss += xv * xv;
          pk[ii] = (short)f2bf(xv);
        }
        *(short8*)(xs + w * 256 + 8 * (cc ^ (w & 7))) = pk;
      }
      xnp[w * 8 + cg] = ss;
      __syncthreads();
      if (wL == L) {
        #pragma unroll
        for (int i = 0; i < 2; ++i)
          #pragma unroll
          for (int kk = 0; kk < 8; ++kk) {
            int r = w32 + i * 16 + m16;
            areg[i * 8 + kk] =
                *(short8*)(xs + r * 256 + 8 * ((kk * 4 + quad) ^ (r & 7)));
          }
      }
      if (tid < 64) {
        float s2 = 0.0f;
        #pragma unroll
        for (int u = 0; u < 8; ++u) s2 += xnp[tid * 8 + u];
        xna[L * 64 + tid] = s2;
      }
    }
  }
  __syncthreads();                           // xs dead; es dbuf live from here

  float bestv[2][4];
  int   besti[2][4];
  #pragma unroll
  for (int i = 0; i < 2; ++i)
    #pragma unroll
    for (int r = 0; r < 4; ++r) { bestv[i][r] = INFINITY; besti[i][r] = 0; }

  // stage tile t (16 KB) into buffer buf: 2 DMA issues/thread, linear dest
  auto stage = [&](int t, int buf) {
    const char* src = (const char*)e_pre + t * 16384;
    char* dst = smem + buf * 16384;
    #pragma unroll
    for (int j = 0; j < 2; ++j) {
      int off = (j * 8 + wave) * 1024 + lane * 16;
      __builtin_amdgcn_global_load_lds(
          (const __attribute__((address_space(1))) unsigned int*)(src + off),
          (__attribute__((address_space(3))) unsigned int*)(dst + off),
          16, 0, 0);
    }
  };

  // ---- GEMM: 32 code tiles, double-buffered, counted vmcnt ----
  stage(0, 0);
  for (int t = 0; t < 32; ++t) {
    if (t < 31) {
      stage(t + 1, (t + 1) & 1);
      asm volatile("s_waitcnt vmcnt(2)" ::: "memory");   // tile t landed, t+1 in flight
    } else {
      asm volatile("s_waitcnt vmcnt(0)" ::: "memory");
    }
    BARRIER_RAW();
    const unsigned short* eb = (const unsigned short*)(smem + (t & 1) * 16384);
    #pragma unroll
    for (int j = 0; j < 2; ++j) {
      int cL = j * 16 + m16;
      float4v a0 = (float4v)(0.0f), a1 = (float4v)(0.0f);
      #pragma unroll
      for (int kk = 0; kk < 8; ++kk) {
        short8 bfr = *(const short8*)(eb + cL * 256 + 8 * ((kk * 4 + quad) ^ (cL & 7)));
        a0 = __builtin_amdgcn_mfma_f32_16x16x32_bf16(areg[kk],     bfr, a0, 0, 0, 0);
        a1 = __builtin_amdgcn_mfma_f32_16x16x32_bf16(areg[8 + kk], bfr, a1, 0, 0, 0);
      }
      int col = t * 32 + cL;
      float nj = nrm[col];
      #pragma unroll
      for (int r = 0; r < 4; ++r) {
        float s0 = nj - 2.0f * a0[r];
        if (s0 < bestv[0][r]) { bestv[0][r] = s0; besti[0][r] = col; }
        float s1 = nj - 2.0f * a1[r];
        if (s1 < bestv[1][r]) { bestv[1][r] = s1; besti[1][r] = col; }
      }
    }
    BARRIER_RAW();
  }

  // ---- cross-lane argmin over the 16 col-lanes (tie -> smaller idx) ----
  #pragma unroll
  for (int msk = 1; msk <= 8; msk <<= 1) {
    #pragma unroll
    for (int i = 0; i < 2; ++i)
      #pragma unroll
      for (int r = 0; r < 4; ++r) {
        float ov = __shfl_xor(bestv[i][r], msk, 64);
        int   oi = __shfl_xor(besti[i][r], msk, 64);
        if (ov < bestv[i][r] || (ov == bestv[i][r] && oi < besti[i][r])) {
          bestv[i][r] = ov; besti[i][r] = oi;
        }
      }
  }

  // ---- indices + loss (loss = sum(||x||^2 + bestv), bestv = ||q||^2-2x.q) ----
  float lsum = 0.0f;
  if (m16 == 0) {
    #pragma unroll
    for (int i = 0; i < 2; ++i)
      #pragma unroll
      for (int r = 0; r < 4; ++r) {
        int row = wave * 32 + i * 16 + quad * 4 + r;
        fi[row] = besti[i][r];
        lsum += bestv[i][r] + xna[row];
      }
  }
  #pragma unroll
  for (int msk = 1; msk < 64; msk <<= 1) lsum += __shfl_xor(lsum, msk, 64);
  if (lane == 0) prt[wave] = lsum;
  __syncthreads();                            // fi visible; GEMM reads done; qs free
  if (tid == 0) {
    float s = 0.0f;
    #pragma unroll
    for (int u = 0; u < 8; ++u) s += prt[u];
    atomicAdd(loss_acc, s);
  }

  // ---- phase 2: gather exact fp32 e rows, swizzled LDS transpose, out ----
  for (int L = 0; L < 4; ++L) {
    int line = line0 + L;
    float* ob = out + 1 + (line >> 6) * 1048576 + (line & 63) * 64;
    int w = tid >> 3, dg = tid & 7;
    int idx = fi[L * 64 + w];
    const float* er = e_fp + idx * 256;
    int swz = (w >> 2) & 7;
    for (int h2 = 0; h2 < 2; ++h2) {
      #pragma unroll
      for (int j = 0; j < 4; ++j) {
        int c = dg + 8 * j;                   // 16B chunk within 128-dim half
        float4v qv = *(const float4v*)(er + h2 * 128 + c * 4);
        *(float4v*)(qs + w * 128 + (c ^ swz) * 4) = qv;
      }
      __syncthreads();
      #pragma unroll
      for (int it = 0; it < 4; ++it) {
        int dl = it * 32 + wave * 4 + quad;   // 0..127
        int slot = (dl >> 2) ^ (m16 & 7);
        float4v ov;
        #pragma unroll
        for (int k = 0; k < 4; ++k)
          ov[k] = qs[(m16 * 4 + k) * 128 + slot * 4 + (dl & 3)];
        *(float4v*)(ob + (h2 * 128 + dl) * 4096 + m16 * 4) = ov;
      }
      __syncthreads();
    }
  }
}

__global__ void vq_fin(const float* __restrict__ loss_acc,
                       const float* __restrict__ beta,
                       float* __restrict__ out) {
  out[0] = (1.0f + beta[0]) * loss_acc[0] / 33554432.0f;
}

extern "C" void kernel_launch(void* const* d_in, const int* in_sizes, int n_in,
                              void* d_out, int out_size, void* d_ws, size_t ws_size,
                              hipStream_t stream) {
  const float* xin  = (const float*)d_in[0];
  const float* emb  = (const float*)d_in[1];
  const float* beta = (const float*)d_in[2];
  float* out = (float*)d_out;
  float* loss_acc = (float*)d_ws;                                // 4 B
  float* norms = (float*)((char*)d_ws + 4096);                   // 4 KB
  unsigned short* e_pre = (unsigned short*)((char*)d_ws + 8192); // 512 KB

  hipMemsetAsync(d_ws, 0, 4, stream);
  vq_prep<<<256, 256, 0, stream>>>(emb, e_pre, norms);
  vq_main<<<512, 512, 0, stream>>>(xin, emb, e_pre, norms, out, loss_acc);
  vq_fin<<<1, 1, 0, stream>>>(loss_acc, beta, out);
}